// Round 5
// baseline (366.788 us; speedup 1.0000x reference)
//
#include <hip/hip_runtime.h>
#include <hip/hip_bf16.h>
#include <stdint.h>

#define BATCH 16
#define CDIM 1024
#define HWDIM 1024
#define PSTRIDE 2048   // fp16 elements per packed row of the S buffer (4096 B)
#define TILE_E (256 * 64)
#define NTK 16         // K/64 for both GEMMs (K = 1024)

typedef _Float16 half_t;
typedef _Float16 half8 __attribute__((ext_vector_type(8)));
typedef float floatx4 __attribute__((ext_vector_type(4)));

__device__ static inline void gld_lds16(const half_t* g, half_t* l) {
    __builtin_amdgcn_global_load_lds(
        (__attribute__((address_space(1))) void*)(void*)g,
        (__attribute__((address_space(3))) void*)l, 16, 0, 0);
}

__device__ __forceinline__ half8 ld8(const char* p) { return *(const half8*)p; }

template <int MB, int NB>
__device__ __forceinline__ void mfma16(floatx4 (&acc)[8][4],
                                       const half8 (&a4)[4][2],
                                       const half8 (&b2)[2][2]) {
#pragma unroll
    for (int mt = 0; mt < 4; ++mt)
#pragma unroll
        for (int nt = 0; nt < 2; ++nt)
#pragma unroll
            for (int ks = 0; ks < 2; ++ks)
                acc[MB + mt][NB + nt] = __builtin_amdgcn_mfma_f32_16x16x32_f16(
                    a4[mt][ks], b2[nt][ks], acc[MB + mt][NB + nt], 0, 0, 0);
}

// Staging register block: 2 rows x 8 f32 (one STG unit = 32 B x 2 rows).
struct St4 { float4 a, b, c, d; };

__device__ __forceinline__ void stld(const float* g, size_t s, St4& r) {
    r.a = *(const float4*)g;
    r.b = *(const float4*)(g + 4);
    r.c = *(const float4*)(g + 64 * s);
    r.d = *(const float4*)(g + 64 * s + 4);
}

__device__ __forceinline__ void stwr(half_t* l, const St4& r) {
    half8 v0, v1;
    v0[0] = (half_t)r.a.x; v0[1] = (half_t)r.a.y; v0[2] = (half_t)r.a.z; v0[3] = (half_t)r.a.w;
    v0[4] = (half_t)r.b.x; v0[5] = (half_t)r.b.y; v0[6] = (half_t)r.b.z; v0[7] = (half_t)r.b.w;
    v1[0] = (half_t)r.c.x; v1[1] = (half_t)r.c.y; v1[2] = (half_t)r.c.z; v1[3] = (half_t)r.c.w;
    v1[4] = (half_t)r.d.x; v1[5] = (half_t)r.d.y; v1[6] = (half_t)r.d.z; v1[7] = (half_t)r.d.w;
    *(half8*)l = v0;
    *(half8*)(l + 4096) = v1;
}

// ---------------------------------------------------------------------------
// 256x256x(K=1024) NT GEMM body, fp16 gload_lds version (used by GEMM2).
// 8-phase schedule (T2+T3+T4+T5) — unchanged, verified working.
// ---------------------------------------------------------------------------
__device__ __forceinline__ void gemm8p(const half_t* __restrict__ Ag, size_t sA,
                                       const half_t* __restrict__ Bg, size_t sB,
                                       int i0, int j0,
                                       half_t* lA, half_t* lB,
                                       floatx4 (&acc)[8][4]) {
    const int tid = threadIdx.x;
    const int lane = tid & 63;
    const int wave = tid >> 6;
    const int wm = wave >> 2, wn = wave & 3;
    const int fr = lane & 15, hi = lane >> 4;
    const int sw = (fr & 7) << 4;
    const int o0 = fr * 128 + ((hi * 16) ^ sw);
    const int o1 = fr * 128 + ((hi * 16 + 64) ^ sw);

    const int r0 = tid >> 3;
    const int scol = ((tid & 7) ^ (r0 & 7)) * 8;
    const half_t* pa = Ag + (size_t)(i0 + r0) * sA + scol;
    const half_t* pb = Bg + (size_t)(j0 + r0) * sB + scol;

#pragma unroll
    for (int a = 0; a < 8; ++a)
#pragma unroll
        for (int b = 0; b < 4; ++b) acc[a][b] = (floatx4){0.f, 0.f, 0.f, 0.f};

#define STG_A(tt, h)                                                      \
    do {                                                                  \
        const half_t* g_ = pa + (size_t)(h) * 128 * sA + (tt) * 64;       \
        half_t* l_ = lA + ((tt) & 1) * TILE_E + (h) * 8192 + tid * 8;     \
        gld_lds16(g_, l_);                                                \
        gld_lds16(g_ + 64 * sA, l_ + 4096);                               \
    } while (0)
#define STG_B(tt, h)                                                      \
    do {                                                                  \
        const half_t* g_ = pb + (size_t)(h) * 128 * sB + (tt) * 64;       \
        half_t* l_ = lB + ((tt) & 1) * TILE_E + (h) * 8192 + tid * 8;     \
        gld_lds16(g_, l_);                                                \
        gld_lds16(g_ + 64 * sB, l_ + 4096);                               \
    } while (0)

    STG_A(0, 0); STG_B(0, 0); STG_A(0, 1); STG_B(0, 1);
    STG_B(1, 0); STG_A(1, 0); STG_B(1, 1);
    asm volatile("s_waitcnt vmcnt(6)" ::: "memory");
    __builtin_amdgcn_s_barrier();

    half8 af[4][2], bf0[2][2], bf1[2][2];

#pragma unroll 2
    for (int t = 0; t < NTK; ++t) {
        const char* aw = (const char*)(lA + (t & 1) * TILE_E) + wm * 8192;
        const char* bw = (const char*)(lB + (t & 1) * TILE_E) + wn * 4096;

        // ---- P0
#pragma unroll
        for (int mt = 0; mt < 4; ++mt) {
            af[mt][0] = ld8(aw + mt * 2048 + o0);
            af[mt][1] = ld8(aw + mt * 2048 + o1);
        }
#pragma unroll
        for (int nt = 0; nt < 2; ++nt) {
            bf0[nt][0] = ld8(bw + nt * 2048 + o0);
            bf0[nt][1] = ld8(bw + nt * 2048 + o1);
        }
        if (t + 1 < NTK) STG_A(t + 1, 1);
        __builtin_amdgcn_s_barrier();
        asm volatile("s_waitcnt lgkmcnt(0)" ::: "memory");
        __builtin_amdgcn_s_setprio(1);
        mfma16<0, 0>(acc, af, bf0);
        __builtin_amdgcn_s_setprio(0);
        __builtin_amdgcn_sched_barrier(0);
        __builtin_amdgcn_s_barrier();

        // ---- P1
#pragma unroll
        for (int nt = 0; nt < 2; ++nt) {
            bf1[nt][0] = ld8(bw + 16384 + nt * 2048 + o0);
            bf1[nt][1] = ld8(bw + 16384 + nt * 2048 + o1);
        }
        if (t + 2 < NTK) STG_B(t + 2, 0);
        __builtin_amdgcn_s_barrier();
        asm volatile("s_waitcnt lgkmcnt(0)" ::: "memory");
        __builtin_amdgcn_s_setprio(1);
        mfma16<0, 2>(acc, af, bf1);
        __builtin_amdgcn_s_setprio(0);
        __builtin_amdgcn_sched_barrier(0);
        __builtin_amdgcn_s_barrier();

        // ---- P2
#pragma unroll
        for (int mt = 0; mt < 4; ++mt) {
            af[mt][0] = ld8(aw + 16384 + mt * 2048 + o0);
            af[mt][1] = ld8(aw + 16384 + mt * 2048 + o1);
        }
        if (t + 2 < NTK) STG_A(t + 2, 0);
        __builtin_amdgcn_s_barrier();
        asm volatile("s_waitcnt lgkmcnt(0)" ::: "memory");
        __builtin_amdgcn_s_setprio(1);
        mfma16<4, 2>(acc, af, bf1);
        __builtin_amdgcn_s_setprio(0);
        __builtin_amdgcn_sched_barrier(0);
        __builtin_amdgcn_s_barrier();

        // ---- P3
        if (t + 2 < NTK) STG_B(t + 2, 1);
        if (t < NTK - 2)
            asm volatile("s_waitcnt vmcnt(6)" ::: "memory");
        else
            asm volatile("s_waitcnt vmcnt(0)" ::: "memory");
        __builtin_amdgcn_s_barrier();
        __builtin_amdgcn_s_setprio(1);
        mfma16<4, 0>(acc, af, bf0);
        __builtin_amdgcn_s_setprio(0);
        __builtin_amdgcn_sched_barrier(0);
        __builtin_amdgcn_s_barrier();
    }
#undef STG_A
#undef STG_B
}

// ---------------------------------------------------------------------------
// f32-source variant (used by GEMM1): reads f32 A/B panels, converts to fp16
// during staging. Staging = reg-load (issued at the old STG slot) + deferred
// cvt+ds_write ONE PHASE LATER (T14 async-split). LDS image identical to the
// fp16 version (linear dest, pre-swizzled source cols) -> read side unchanged.
// Deferral audit (write -> first read, barriers in between >= 3):
//   B1(t+1): ld t-1.P3, wr t.P0,  read (t+1).P1
//   A1(t+1): ld t.P0,   wr t.P1,  read (t+1).P2
//   B0(t+2): ld t.P1,   wr t.P2,  read (t+2).P0
//   A0(t+2): ld t.P2,   wr t.P3,  read (t+2).P0
// Each write's target region was last READ >= 2 barriers earlier (readers
// drain lgkmcnt(0) in their own phase before the barrier the writer passed).
// ---------------------------------------------------------------------------
__device__ __forceinline__ void gemm8p32(const float* __restrict__ Ag, size_t sA,
                                         const float* __restrict__ Bg, size_t sB,
                                         int i0, int j0,
                                         half_t* lA, half_t* lB,
                                         floatx4 (&acc)[8][4]) {
    const int tid = threadIdx.x;
    const int lane = tid & 63;
    const int wave = tid >> 6;
    const int wm = wave >> 2, wn = wave & 3;
    const int fr = lane & 15, hi = lane >> 4;
    const int sw = (fr & 7) << 4;
    const int o0 = fr * 128 + ((hi * 16) ^ sw);
    const int o1 = fr * 128 + ((hi * 16 + 64) ^ sw);

    const int r0 = tid >> 3;
    const int scol = ((tid & 7) ^ (r0 & 7)) * 8;   // same logical cols as fp16 ver.
    const float* pa = Ag + (size_t)(i0 + r0) * sA + scol;
    const float* pb = Bg + (size_t)(j0 + r0) * sB + scol;

#pragma unroll
    for (int a = 0; a < 8; ++a)
#pragma unroll
        for (int b = 0; b < 4; ++b) acc[a][b] = (floatx4){0.f, 0.f, 0.f, 0.f};

    St4 sA1, sB0, sA0, sB1;

    // Prologue: inline-stage {A0,B0,A1,B1}(0), B0(1), A0(1); defer-load B1(1).
    stld(pa, sA, sA0);                     stwr(lA + tid * 8, sA0);
    stld(pb, sB, sB0);                     stwr(lB + tid * 8, sB0);
    stld(pa + (size_t)128 * sA, sA, sA1);  stwr(lA + 8192 + tid * 8, sA1);
    stld(pb + (size_t)128 * sB, sB, sB1);  stwr(lB + 8192 + tid * 8, sB1);
    stld(pb + 64, sB, sB0);                stwr(lB + TILE_E + tid * 8, sB0);
    stld(pa + 64, sA, sA0);                stwr(lA + TILE_E + tid * 8, sA0);
    stld(pb + (size_t)128 * sB + 64, sB, sB1);     // B1(1) in regs
    asm volatile("s_waitcnt lgkmcnt(0)" ::: "memory");
    __builtin_amdgcn_s_barrier();

    half8 af[4][2], bf0[2][2], bf1[2][2];

#pragma unroll 2
    for (int t = 0; t < NTK; ++t) {
        const char* aw = (const char*)(lA + (t & 1) * TILE_E) + wm * 8192;
        const char* bw = (const char*)(lB + (t & 1) * TILE_E) + wn * 4096;
        half_t* nA = lA + ((t + 1) & 1) * TILE_E + tid * 8;  // next-buf bases
        half_t* nB = lB + ((t + 1) & 1) * TILE_E + tid * 8;
        half_t* cA = lA + (t & 1) * TILE_E + tid * 8;        // cur-buf (t+2 targets)
        half_t* cB = lB + (t & 1) * TILE_E + tid * 8;

        // ---- P0: ds_read A-h0 + B-h0; WR B1(t+1); LD A1(t+1)
#pragma unroll
        for (int mt = 0; mt < 4; ++mt) {
            af[mt][0] = ld8(aw + mt * 2048 + o0);
            af[mt][1] = ld8(aw + mt * 2048 + o1);
        }
#pragma unroll
        for (int nt = 0; nt < 2; ++nt) {
            bf0[nt][0] = ld8(bw + nt * 2048 + o0);
            bf0[nt][1] = ld8(bw + nt * 2048 + o1);
        }
        if (t + 1 < NTK) {
            stwr(nB + 8192, sB1);
            stld(pa + (size_t)128 * sA + (t + 1) * 64, sA, sA1);
        }
        __builtin_amdgcn_s_barrier();
        asm volatile("s_waitcnt lgkmcnt(0)" ::: "memory");
        __builtin_amdgcn_s_setprio(1);
        mfma16<0, 0>(acc, af, bf0);
        __builtin_amdgcn_s_setprio(0);
        __builtin_amdgcn_sched_barrier(0);
        __builtin_amdgcn_s_barrier();

        // ---- P1: ds_read B-h1; WR A1(t+1); LD B0(t+2)
#pragma unroll
        for (int nt = 0; nt < 2; ++nt) {
            bf1[nt][0] = ld8(bw + 16384 + nt * 2048 + o0);
            bf1[nt][1] = ld8(bw + 16384 + nt * 2048 + o1);
        }
        if (t + 1 < NTK) stwr(nA + 8192, sA1);
        if (t + 2 < NTK) stld(pb + (t + 2) * 64, sB, sB0);
        __builtin_amdgcn_s_barrier();
        asm volatile("s_waitcnt lgkmcnt(0)" ::: "memory");
        __builtin_amdgcn_s_setprio(1);
        mfma16<0, 2>(acc, af, bf1);
        __builtin_amdgcn_s_setprio(0);
        __builtin_amdgcn_sched_barrier(0);
        __builtin_amdgcn_s_barrier();

        // ---- P2: ds_read A-h1; WR B0(t+2); LD A0(t+2)
#pragma unroll
        for (int mt = 0; mt < 4; ++mt) {
            af[mt][0] = ld8(aw + 16384 + mt * 2048 + o0);
            af[mt][1] = ld8(aw + 16384 + mt * 2048 + o1);
        }
        if (t + 2 < NTK) {
            stwr(cB, sB0);
            stld(pa + (t + 2) * 64, sA, sA0);
        }
        __builtin_amdgcn_s_barrier();
        asm volatile("s_waitcnt lgkmcnt(0)" ::: "memory");
        __builtin_amdgcn_s_setprio(1);
        mfma16<4, 2>(acc, af, bf1);
        __builtin_amdgcn_s_setprio(0);
        __builtin_amdgcn_sched_barrier(0);
        __builtin_amdgcn_s_barrier();

        // ---- P3: WR A0(t+2); LD B1(t+2); MFMA (reg-only)
        if (t + 2 < NTK) {
            stwr(cA, sA0);
            stld(pb + (size_t)128 * sB + (t + 2) * 64, sB, sB1);
        }
        __builtin_amdgcn_s_barrier();
        __builtin_amdgcn_s_setprio(1);
        mfma16<4, 0>(acc, af, bf0);
        __builtin_amdgcn_s_setprio(0);
        __builtin_amdgcn_sched_barrier(0);
        __builtin_amdgcn_s_barrier();
    }
}

// XCD-chunked bijective swizzle: 256 wg, 32 per XCD = 2 whole batches per XCD.
__device__ __forceinline__ void tile_coords(int& bz, int& i0, int& j0) {
    const int flat = blockIdx.x + (blockIdx.y << 4);
    const int w = ((flat & 7) << 5) + (flat >> 3);
    bz = w >> 4;
    const int tl = w & 15;
    i0 = (tl & 3) << 8;
    j0 = (tl >> 2) << 8;
}

// ---------------------------------------------------------------------------
// Softmax over each fp32 row of S (1024); packs P (fp16) into the first
// 2048 B of the row. Wave-per-row, shuffle reductions. grid 4096, block 256.
// ---------------------------------------------------------------------------
__global__ __launch_bounds__(256) void k_softmax(float* __restrict__ S) {
    const int wave = threadIdx.x >> 6;
    const int lane = threadIdx.x & 63;
    float* rp = S + ((size_t)blockIdx.x * 4 + wave) * CDIM;

    float4 v[4];
#pragma unroll
    for (int j = 0; j < 4; ++j) v[j] = ((const float4*)rp)[lane + 64 * j];

    float m = -1e30f;
#pragma unroll
    for (int j = 0; j < 4; ++j)
        m = fmaxf(m, fmaxf(fmaxf(v[j].x, v[j].y), fmaxf(v[j].z, v[j].w)));
#pragma unroll
    for (int off = 32; off > 0; off >>= 1) m = fmaxf(m, __shfl_xor(m, off));

    float e[4][4];
    float s = 0.f;
#pragma unroll
    for (int j = 0; j < 4; ++j) {
        e[j][0] = __expf(v[j].x - m); e[j][1] = __expf(v[j].y - m);
        e[j][2] = __expf(v[j].z - m); e[j][3] = __expf(v[j].w - m);
        s += e[j][0] + e[j][1] + e[j][2] + e[j][3];
    }
#pragma unroll
    for (int off = 32; off > 0; off >>= 1) s += __shfl_xor(s, off);
    const float inv = 1.0f / s;

#pragma unroll
    for (int j = 0; j < 4; ++j) {
        half_t p[4];
        p[0] = (half_t)(e[j][0] * inv); p[1] = (half_t)(e[j][1] * inv);
        p[2] = (half_t)(e[j][2] * inv); p[3] = (half_t)(e[j][3] * inv);
        ((uint2*)rp)[lane + 64 * j] = *(const uint2*)p;
    }
}

// ---------------------------------------------------------------------------
// Transpose a[b] (C x HW, f32) -> fp16 At rows in the dead half of each packed
// S row (offset +1024 fp16). Runs AFTER softmax. grid (16,16,16). (unchanged)
// ---------------------------------------------------------------------------
__global__ __launch_bounds__(256) void k_transpose(const float* __restrict__ A,
                                                   half_t* __restrict__ SP) {
    const int bz = blockIdx.z;
    const int t0 = blockIdx.x * 64;  // HW block
    const int j0 = blockIdx.y * 64;  // C block
    const float* Ap = A + (size_t)bz * CDIM * HWDIM;
    half_t* Atp = SP + (size_t)bz * CDIM * PSTRIDE + 1024;

    __shared__ half_t tile[64][68];
    const int lr = threadIdx.x >> 4;         // 0..15
    const int lc = (threadIdx.x & 15) * 4;   // 0..60
#pragma unroll
    for (int r = 0; r < 4; ++r) {
        const float* src = Ap + (size_t)(j0 + lr + r * 16) * HWDIM + t0 + lc;
        float4 f = *(const float4*)src;
        half_t t4[4];
        t4[0] = (half_t)f.x; t4[1] = (half_t)f.y;
        t4[2] = (half_t)f.z; t4[3] = (half_t)f.w;
        *(uint2*)&tile[lr + r * 16][lc] = *(const uint2*)t4;
    }
    __syncthreads();
#pragma unroll
    for (int r = 0; r < 4; ++r) {
        const int trow = lr + r * 16;
        half_t tmp[4];
#pragma unroll
        for (int e = 0; e < 4; ++e) tmp[e] = tile[lc + e][trow];
        *(uint2*)(Atp + (size_t)(t0 + trow) * PSTRIDE + j0 + lc) = *(uint2*)tmp;
    }
}

// ---------------------------------------------------------------------------
// GEMM1: S[b][i][j] = sum_k b[b][i][k] * c[b][j][k]  (NT, f32 in via fused
// cvt staging, f32 out). 256^2 8-phase. grid (16,16), block 512.
// ---------------------------------------------------------------------------
__global__ __launch_bounds__(512, 2) void k_gemm1(const float* __restrict__ Bm,
                                                  const float* __restrict__ Cm,
                                                  float* __restrict__ S) {
    __shared__ half_t lA[2 * TILE_E];
    __shared__ half_t lB[2 * TILE_E];
    int bz, i0, j0;
    tile_coords(bz, i0, j0);

    floatx4 acc[8][4];
    gemm8p32(Bm + (size_t)bz * CDIM * HWDIM, HWDIM,
             Cm + (size_t)bz * CDIM * HWDIM, HWDIM, i0, j0, lA, lB, acc);

    float* Sp = S + (size_t)bz * CDIM * CDIM;
    const int lane = threadIdx.x & 63;
    const int wave = threadIdx.x >> 6;
    const int wm = wave >> 2, wn = wave & 3;
    const int er = (lane >> 4) * 4;
    const int ec = lane & 15;
#pragma unroll
    for (int mt = 0; mt < 8; ++mt) {
        const int row0 = i0 + ((mt >> 2) << 7) + wm * 64 + (mt & 3) * 16 + er;
#pragma unroll
        for (int nt = 0; nt < 4; ++nt) {
            const int col = j0 + ((nt >> 1) << 7) + wn * 32 + (nt & 1) * 16 + ec;
            float* dst = Sp + (size_t)row0 * CDIM + col;
#pragma unroll
            for (int r = 0; r < 4; ++r) dst[(size_t)r * CDIM] = acc[mt][nt][r];
        }
    }
}

// ---------------------------------------------------------------------------
// GEMM2: Out[b][i][t] = sum_j P[b][i][j]*At[b][t][j] + a[b][i][t] (f32 out).
// P and At (fp16) both live in the packed S buffer, row stride PSTRIDE.
// 256^2 8-phase, fp16 gload_lds body. grid (16,16), block 512. (unchanged)
// ---------------------------------------------------------------------------
__global__ __launch_bounds__(512, 2) void k_gemm2(const half_t* __restrict__ SP,
                                                  const float* __restrict__ Aorig,
                                                  float* __restrict__ Out) {
    __shared__ half_t lA[2 * TILE_E];
    __shared__ half_t lB[2 * TILE_E];
    int bz, i0, t0;
    tile_coords(bz, i0, t0);

    const half_t* Pp = SP + (size_t)bz * CDIM * PSTRIDE;
    const half_t* Bp = Pp + 1024;  // At rows

    floatx4 acc[8][4];
    gemm8p(Pp, PSTRIDE, Bp, PSTRIDE, i0, t0, lA, lB, acc);

    const float* ap = Aorig + (size_t)bz * CDIM * HWDIM;
    float* op = Out + (size_t)bz * CDIM * HWDIM;
    const int lane = threadIdx.x & 63;
    const int wave = threadIdx.x >> 6;
    const int wm = wave >> 2, wn = wave & 3;
    const int er = (lane >> 4) * 4;
    const int ec = lane & 15;
#pragma unroll
    for (int mt = 0; mt < 8; ++mt) {
        const int row0 = i0 + ((mt >> 2) << 7) + wm * 64 + (mt & 3) * 16 + er;
#pragma unroll
        for (int nt = 0; nt < 4; ++nt) {
            const int col = t0 + ((nt >> 1) << 7) + wn * 32 + (nt & 1) * 16 + ec;
#pragma unroll
            for (int r = 0; r < 4; ++r) {
                const size_t idx = (size_t)(row0 + r) * HWDIM + col;
                op[idx] = acc[mt][nt][r] + ap[idx];
            }
        }
    }
}

extern "C" void kernel_launch(void* const* d_in, const int* in_sizes, int n_in,
                              void* d_out, int out_size, void* d_ws, size_t ws_size,
                              hipStream_t stream) {
    const float* a = (const float*)d_in[0];
    const float* b = (const float*)d_in[1];
    const float* c = (const float*)d_in[2];
    float* out = (float*)d_out;

    float* S = (float*)d_ws;   // 64 MB: fp32 scores -> {P | At} packed

    k_gemm1<<<dim3(16, 16), 512, 0, stream>>>(b, c, S);
    k_softmax<<<dim3(BATCH * CDIM / 4), 256, 0, stream>>>(S);
    k_transpose<<<dim3(16, 16, 16), 256, 0, stream>>>(a, (half_t*)S);
    k_gemm2<<<dim3(16, 16), 512, 0, stream>>>((const half_t*)S, a, out);
}